// Round 2
// baseline (405.668 us; speedup 1.0000x reference)
//
#include <hip/hip_runtime.h>
#include <hip/hip_bf16.h>

// GAT (2-layer, 8-head) on gfx950. Inputs f32 (adj int32), outputs f32.
// d_out = [h2: 2048*512 | att1: 8*2048*2048 | att2: 8*2048*2048] float32.

typedef __attribute__((ext_vector_type(8))) short bf16x8;
typedef __attribute__((ext_vector_type(4))) float f32x4;

__device__ __forceinline__ float bf2f(unsigned short u) {
    return __uint_as_float(((unsigned int)u) << 16);
}
__device__ __forceinline__ unsigned short f2bf(float f) {
    __hip_bfloat16 h = __float2bfloat16(f);
    return __builtin_bit_cast(unsigned short, h);
}
__device__ __forceinline__ float elu1(float x) { return x > 0.f ? x : expm1f(x); }

// order-preserving float->uint key for atomicMax
__device__ __forceinline__ unsigned fkey(float f) {
    unsigned b = __float_as_uint(f);
    return (b & 0x80000000u) ? ~b : (b | 0x80000000u);
}
__device__ __forceinline__ float funkey(unsigned k) {
    return __uint_as_float((k & 0x80000000u) ? (k ^ 0x80000000u) : ~k);
}

// ---------------------------------------------------------------------------
// adj [2048][2048] int32 -> bitmask [2048][64] u32 (u64 stores via ballot).
// ---------------------------------------------------------------------------
__global__ __launch_bounds__(256) void adjbits_kernel(
    const int* __restrict__ adj, unsigned long long* __restrict__ gbits) {
    int g = blockIdx.x * 256 + threadIdx.x;  // 4194304 threads
    unsigned long long m = __ballot(adj[g] > 0);
    if ((threadIdx.x & 63) == 0) gbits[g >> 6] = m;
}

// ---------------------------------------------------------------------------
// Reorder W [8][512][64] (f32) into split-bf16 MFMA B-fragment packing.
// Also inits per-head s2-max accumulator (runs before gemm1 each layer).
// ---------------------------------------------------------------------------
__global__ __launch_bounds__(256) void reorder_w_kernel(
    const float* __restrict__ W, unsigned short* __restrict__ WpHi,
    unsigned short* __restrict__ WpLo, unsigned* __restrict__ Mmax) {
    if (blockIdx.x == 0 && threadIdx.x < 8) Mmax[threadIdx.x] = 0u;
    int i = blockIdx.x * 256 + threadIdx.x;  // 262144 threads
    int o = i & 63;
    int k = (i >> 6) & 511;
    int h = i >> 15;
    float v = W[i];
    unsigned short hi = f2bf(v);
    unsigned short lo = f2bf(v - bf2f(hi));
    long idx = (((h * 16) + (k >> 5)) * 64 + o) * 32 + (k & 31);
    WpHi[idx] = hi;
    WpLo[idx] = lo;
}

// ---------------------------------------------------------------------------
// GEMM1: Wh[h] = A[2048][512](f32) @ W[h][512][64], split-bf16 (3 MFMAs).
// 2-way K-split: block = 4 waves over (2 row-halves x 2 K-halves), 32 rows.
// Grid = 8 heads * 64 row-tiles = 512 blocks. LDS-reduce K partials.
// Epilogue (kw==0 waves): s1/s2 shfl-reduction + bf16 fragment-packed Whp +
// per-head unmasked max of s2 via atomicMax (softmax shift bound).
// ---------------------------------------------------------------------------
__global__ __launch_bounds__(256, 2) void gemm1_kernel(
    const float* __restrict__ A,
    const unsigned short* __restrict__ BpHi, const unsigned short* __restrict__ BpLo,
    const float* __restrict__ avec,
    unsigned short* __restrict__ Whp, float* __restrict__ s1, float* __restrict__ s2,
    unsigned* __restrict__ Mmax) {
    __shared__ float accred[2][64][20];  // [rowhalf][col][16 rows + pad]
    const int bx   = blockIdx.x;   // 512
    const int h    = bx >> 6;
    const int mt   = bx & 63;
    const int tid  = threadIdx.x;
    const int wave = tid >> 6;
    const int lane = tid & 63;
    const int quad = lane >> 4;
    const int m16  = lane & 15;
    const int rw   = wave & 1;   // row half (16 rows each)
    const int kw   = wave >> 1;  // K half (256 each)
    const int rowbase = mt * 32 + rw * 16;

    const float* Arow = A + (long)(rowbase + m16) * 512 + kw * 256 + quad * 8;
    const long boff = ((long)(h * 16 + kw * 8) * 64 + m16) * 32 + quad * 8;
    const unsigned short* BH = BpHi + boff;
    const unsigned short* BL = BpLo + boff;

    f32x4 acc[4];
#pragma unroll
    for (int t = 0; t < 4; ++t)
#pragma unroll
        for (int r = 0; r < 4; ++r) acc[t][r] = 0.f;

    for (int kb = 0; kb < 8; ++kb) {
        const float* ap = Arow + kb * 32;
        bf16x8 ahi, alo;
#pragma unroll
        for (int j = 0; j < 8; ++j) {
            float v = ap[j];
            unsigned short hv = f2bf(v);
            ahi[j] = (short)hv;
            alo[j] = (short)f2bf(v - bf2f(hv));
        }
        const unsigned short* bh0 = BH + (long)kb * 2048;
        const unsigned short* bl0 = BL + (long)kb * 2048;
#pragma unroll
        for (int t = 0; t < 4; ++t) {
            bf16x8 bh = *reinterpret_cast<const bf16x8*>(bh0 + t * 512);
            bf16x8 bl = *reinterpret_cast<const bf16x8*>(bl0 + t * 512);
            acc[t] = __builtin_amdgcn_mfma_f32_16x16x32_bf16(alo, bh, acc[t], 0, 0, 0);
            acc[t] = __builtin_amdgcn_mfma_f32_16x16x32_bf16(ahi, bl, acc[t], 0, 0, 0);
            acc[t] = __builtin_amdgcn_mfma_f32_16x16x32_bf16(ahi, bh, acc[t], 0, 0, 0);
        }
    }

    if (kw == 1) {
#pragma unroll
        for (int t = 0; t < 4; ++t)
            *reinterpret_cast<f32x4*>(&accred[rw][t * 16 + m16][quad * 4]) = acc[t];
    }
    __syncthreads();
    if (kw == 1) return;

#pragma unroll
    for (int t = 0; t < 4; ++t) {
        f32x4 o = *reinterpret_cast<const f32x4*>(&accred[rw][t * 16 + m16][quad * 4]);
#pragma unroll
        for (int r = 0; r < 4; ++r) acc[t][r] += o[r];
    }

    // ---- s1/s2 epilogue ----
    float aS[4], aD[4];
#pragma unroll
    for (int t = 0; t < 4; ++t) {
        aS[t] = avec[(h << 7) + t * 16 + m16];
        aD[t] = avec[(h << 7) + 64 + t * 16 + m16];
    }
    float s2max = -INFINITY;
#pragma unroll
    for (int r = 0; r < 4; ++r) {
        float t1 = 0.f, t2 = 0.f;
#pragma unroll
        for (int t = 0; t < 4; ++t) {
            float v = acc[t][r];
            t1 = fmaf(v, aS[t], t1);
            t2 = fmaf(v, aD[t], t2);
        }
#pragma unroll
        for (int off = 1; off < 16; off <<= 1) {
            t1 += __shfl_xor(t1, off);
            t2 += __shfl_xor(t2, off);
        }
        s2max = fmaxf(s2max, t2);
        if (m16 == 0) {
            int row = rowbase + quad * 4 + r;
            s1[(h << 11) + row] = t1;
            s2[(h << 11) + row] = t2;
        }
    }
    // per-head unmasked max of s2 (upper bound for softmax shift)
    s2max = fmaxf(s2max, __shfl_xor(s2max, 16));
    s2max = fmaxf(s2max, __shfl_xor(s2max, 32));
    if (lane == 0) atomicMax(Mmax + h, fkey(s2max));

    // ---- store Wh bf16 fragment-packed (Hi only; PV tolerates bf16) ----
#pragma unroll
    for (int t = 0; t < 4; ++t) {
        const int col = t * 16 + m16;
#pragma unroll
        for (int r = 0; r < 4; ++r) {
            const int row = rowbase + quad * 4 + r;
            long idx = (((long)(h * 64 + (row >> 5)) * 64 + col) << 5) + (row & 31);
            Whp[idx] = f2bf(acc[t][r]);
        }
    }
}

// ---------------------------------------------------------------------------
// Fused attention, 2 passes (was 3):
//  P12: one exp pass -> unnormalized u kept as packed bf16 in 32 VGPRs,
//       l accumulated simultaneously. m = lrelu(s1_i + per-head max s2)
//       (valid upper bound; softmax is shift-invariant).
//  P3 : att = u*invl (LDS-staged packed NT store), PV MFMA on u directly,
//       accumulator scaled by invl[row] in epilogue.
// Block = 256 thr (4 waves), 16 rows; each wave owns a j-quarter.
// ---------------------------------------------------------------------------
__global__ __launch_bounds__(256, 4) void fused_att_kernel(
    const float* __restrict__ s1g, const float* __restrict__ s2g,
    const unsigned int* __restrict__ gbits,
    const unsigned short* __restrict__ Whp,
    const unsigned* __restrict__ Mmax,
    float* __restrict__ att, float* __restrict__ hout) {
    __shared__ unsigned int lbits[16 * 65];   // 16 rows x 64 words, +1 pad
    __shared__ float ls2[2048];
    __shared__ float lsum[4][16];
    __shared__ float linv[16];
    __shared__ float accred[3][64][20];       // waves 1..3 partial PV
    __shared__ f32x4 pstage[4][16][9];        // per-wave P staging

    const int bx   = blockIdx.x;   // 1024
    const int h    = bx >> 7;
    const int row0 = (bx & 127) << 4;
    const int tid  = threadIdx.x;
    const int wq   = tid >> 6;     // wave = j-quarter
    const int lane = tid & 63;
    const int quad = lane >> 4;
    const int m16  = lane & 15;

    // stage adj bits (16 rows x 64 words) + s2 (2048 f32)
#pragma unroll
    for (int i = 0; i < 4; ++i) {
        int idx = i * 256 + tid;
        lbits[(idx >> 6) * 65 + (idx & 63)] = gbits[((row0 + (idx >> 6)) << 6) + (idx & 63)];
    }
    const float4* s2v4 = reinterpret_cast<const float4*>(s2g + (h << 11));
#pragma unroll
    for (int i = 0; i < 2; ++i) {
        int idx = i * 256 + tid;
        reinterpret_cast<float4*>(ls2)[idx] = s2v4[idx];
    }
    __syncthreads();

    const float s1i = s1g[(h << 11) + row0 + m16];
    const float M = funkey(Mmax[h]);
    const float ebar = s1i + M;
    const float m = fmaxf(ebar, 0.2f * ebar);  // lrelu(upper bound) >= all lrelu(e)

    // ---- P12: single exp pass; u (unnormalized) -> bf16 regs; l accumulated --
    bf16x8 uarr[16];
    float lp = 0.f;
#pragma unroll
    for (int i = 0; i < 16; ++i) {
        const int jt = wq * 16 + i;
        unsigned int word = lbits[m16 * 65 + jt] >> (quad * 8);
        float4 sa = *reinterpret_cast<const float4*>(ls2 + jt * 32 + quad * 8);
        float4 sb = *reinterpret_cast<const float4*>(ls2 + jt * 32 + quad * 8 + 4);
        float sv[8] = {sa.x, sa.y, sa.z, sa.w, sb.x, sb.y, sb.z, sb.w};
        bf16x8 uf;
#pragma unroll
        for (int u = 0; u < 8; ++u) {
            float e = s1i + sv[u];
            e = fmaxf(e, 0.2f * e);
            float ex = ((word >> u) & 1u) ? __expf(e - m) : 0.f;
            lp += ex;
            uf[u] = (short)f2bf(ex);
        }
        uarr[i] = uf;
    }
    lp += __shfl_xor(lp, 16);
    lp += __shfl_xor(lp, 32);
    if (lane < 16) lsum[wq][m16] = lp;
    __syncthreads();
    const float l = lsum[0][m16] + lsum[1][m16] + lsum[2][m16] + lsum[3][m16];
    const bool am = (l == 0.f);                 // all-masked row
    const float invl = am ? 0.f : 1.f / l;
    const float fb = am ? (1.f / 2048.f) : 0.f; // p = u*invl + fb
    if (wq == 0 && lane < 16) linv[m16] = invl;

    // ---- P3: att write (LDS-staged, packed NT) + PV MFMA on u ----
    f32x4 acc[4];
#pragma unroll
    for (int t = 0; t < 4; ++t)
#pragma unroll
        for (int r = 0; r < 4; ++r) acc[t][r] = 0.f;

    const unsigned short* BW = Whp + ((long)(h << 12) + m16) * 32 + quad * 8;
    float* attbase = att + (long)h * 4194304 + (long)row0 * 2048;
    const int fr = lane >> 3;        // flush row within half (0..7)
    const int fc = lane & 7;         // flush col-block (16B units)

#pragma unroll
    for (int i = 0; i < 16; ++i) {
        const int jt = wq * 16 + i;
        bf16x8 uf = uarr[i];
        float p[8];
#pragma unroll
        for (int u = 0; u < 8; ++u)
            p[u] = fmaf(bf2f((unsigned short)uf[u]), invl, fb);

        // stage P-tile (fragment layout -> row-major) in this wave's LDS region
        f32x4 plo, phi;
        plo[0] = p[0]; plo[1] = p[1]; plo[2] = p[2]; plo[3] = p[3];
        phi[0] = p[4]; phi[1] = p[5]; phi[2] = p[6]; phi[3] = p[7];
        pstage[wq][m16][quad * 2]     = plo;
        pstage[wq][m16][quad * 2 + 1] = phi;

        const unsigned short* b0 = BW + (long)jt * 2048;
#pragma unroll
        for (int t = 0; t < 4; ++t) {
            bf16x8 bf = *reinterpret_cast<const bf16x8*>(b0 + t * 512);
            acc[t] = __builtin_amdgcn_mfma_f32_16x16x32_bf16(uf, bf, acc[t], 0, 0, 0);
        }

        // packed flush: 2 wave-stores, each 8 rows x 128B full lines (NT)
#pragma unroll
        for (int half = 0; half < 2; ++half) {
            const int r = half * 8 + fr;
            f32x4 v = pstage[wq][r][fc];
            __builtin_nontemporal_store(
                v, reinterpret_cast<f32x4*>(attbase + (long)r * 2048 + jt * 32 + fc * 4));
        }
    }

    // ---- reduce partial PV across waves, epilogue by wave 0 (scaled) ----
    if (wq > 0) {
#pragma unroll
        for (int t = 0; t < 4; ++t)
            *reinterpret_cast<f32x4*>(&accred[wq - 1][t * 16 + m16][quad * 4]) = acc[t];
    }
    __syncthreads();
    if (wq == 0) {
#pragma unroll
        for (int t = 0; t < 4; ++t) {
            const int col = t * 16 + m16;
#pragma unroll
            for (int w = 0; w < 3; ++w) {
                f32x4 o = *reinterpret_cast<const f32x4*>(&accred[w][col][quad * 4]);
#pragma unroll
                for (int r = 0; r < 4; ++r) acc[t][r] += o[r];
            }
#pragma unroll
            for (int r = 0; r < 4; ++r) {
                const int row = row0 + quad * 4 + r;
                const float sc = linv[quad * 4 + r];
                hout[(row << 9) + (h << 6) + col] = elu1(elu1(acc[t][r] * sc));
            }
        }
    }
}

// ---------------------------------------------------------------------------
extern "C" void kernel_launch(void* const* d_in, const int* in_sizes, int n_in,
                              void* d_out, int out_size, void* d_ws, size_t ws_size,
                              hipStream_t stream) {
    const float* x  = (const float*)d_in[0];   // [2048][512]
    const int* adj  = (const int*)d_in[1];     // [2048][2048]
    const float* W1 = (const float*)d_in[2];   // [8][512][64]
    const float* a1 = (const float*)d_in[3];   // [8][128]
    const float* W2 = (const float*)d_in[4];
    const float* a2 = (const float*)d_in[5];

    float* out  = (float*)d_out;       // h2 [2048][512]
    float* att1 = out + 1048576;       // [8][2048][2048]
    float* att2 = att1 + 33554432;

    char* w = (char*)d_ws;
    unsigned short* WpHi  = (unsigned short*)(w);             // 512 KB
    unsigned short* WpLo  = (unsigned short*)(w + 524288);    // 512 KB
    unsigned short* Whp   = (unsigned short*)(w + 1048576);   // 2 MB
    float* s1             = (float*)(w + 3145728);            // 64 KB
    float* s2             = (float*)(w + 3211264);            // 64 KB
    unsigned long long* gbits = (unsigned long long*)(w + 3276800);  // 512 KB
    float* x2             = (float*)(w + 3801088);            // 4 MB
    unsigned* Mmax        = (unsigned*)(w + 7995392);         // 32 B

    const unsigned int* gbits32 = (const unsigned int*)gbits;

    adjbits_kernel<<<16384, 256, 0, stream>>>(adj, gbits);

    // ---- layer 1 ----
    reorder_w_kernel<<<1024, 256, 0, stream>>>(W1, WpHi, WpLo, Mmax);
    gemm1_kernel<<<512, 256, 0, stream>>>(x, WpHi, WpLo, a1, Whp, s1, s2, Mmax);
    fused_att_kernel<<<1024, 256, 0, stream>>>(s1, s2, gbits32, Whp, Mmax, att1, x2);

    // ---- layer 2 ----
    reorder_w_kernel<<<1024, 256, 0, stream>>>(W2, WpHi, WpLo, Mmax);
    gemm1_kernel<<<512, 256, 0, stream>>>(x2, WpHi, WpLo, a2, Whp, s1, s2, Mmax);
    fused_att_kernel<<<1024, 256, 0, stream>>>(s1, s2, gbits32, Whp, Mmax, att2, out);
}

// Round 3
// 376.513 us; speedup vs baseline: 1.0774x; 1.0774x over previous
//
#include <hip/hip_runtime.h>
#include <hip/hip_bf16.h>

// GAT (2-layer, 8-head) on gfx950. Inputs f32 (adj int32), outputs f32.
// d_out = [h2: 2048*512 | att1: 8*2048*2048 | att2: 8*2048*2048] float32.

typedef __attribute__((ext_vector_type(8))) short bf16x8;
typedef __attribute__((ext_vector_type(4))) float f32x4;

__device__ __forceinline__ float bf2f(unsigned short u) {
    return __uint_as_float(((unsigned int)u) << 16);
}
__device__ __forceinline__ unsigned short f2bf(float f) {
    __hip_bfloat16 h = __float2bfloat16(f);
    return __builtin_bit_cast(unsigned short, h);
}
__device__ __forceinline__ float elu1(float x) { return x > 0.f ? x : expm1f(x); }

// order-preserving float->uint key for atomicMax
__device__ __forceinline__ unsigned fkey(float f) {
    unsigned b = __float_as_uint(f);
    return (b & 0x80000000u) ? ~b : (b | 0x80000000u);
}
__device__ __forceinline__ float funkey(unsigned k) {
    return __uint_as_float((k & 0x80000000u) ? (k ^ 0x80000000u) : ~k);
}

// ---------------------------------------------------------------------------
// adj [2048][2048] int32 -> bitmask [2048][64] u32 (u64 stores via ballot).
// ---------------------------------------------------------------------------
__global__ __launch_bounds__(256) void adjbits_kernel(
    const int* __restrict__ adj, unsigned long long* __restrict__ gbits) {
    int g = blockIdx.x * 256 + threadIdx.x;  // 4194304 threads
    unsigned long long m = __ballot(adj[g] > 0);
    if ((threadIdx.x & 63) == 0) gbits[g >> 6] = m;
}

// ---------------------------------------------------------------------------
// Reorder W [8][512][64] (f32) into split-bf16 MFMA B-fragment packing.
// Also inits per-head s2-max accumulator (runs before gemm1 each layer).
// ---------------------------------------------------------------------------
__global__ __launch_bounds__(256) void reorder_w_kernel(
    const float* __restrict__ W, unsigned short* __restrict__ WpHi,
    unsigned short* __restrict__ WpLo, unsigned* __restrict__ Mmax) {
    if (blockIdx.x == 0 && threadIdx.x < 8) Mmax[threadIdx.x] = 0u;
    int i = blockIdx.x * 256 + threadIdx.x;  // 262144 threads
    int o = i & 63;
    int k = (i >> 6) & 511;
    int h = i >> 15;
    float v = W[i];
    unsigned short hi = f2bf(v);
    unsigned short lo = f2bf(v - bf2f(hi));
    long idx = (((h * 16) + (k >> 5)) * 64 + o) * 32 + (k & 31);
    WpHi[idx] = hi;
    WpLo[idx] = lo;
}

// ---------------------------------------------------------------------------
// GEMM1: Wh[h] = A[2048][512](f32) @ W[h][512][64], split-bf16 (3 MFMAs).
// 2-way K-split: block = 4 waves over (2 row-halves x 2 K-halves), 32 rows.
// Grid = 8 heads * 64 row-tiles = 512 blocks. LDS-reduce K partials.
// Epilogue (kw==0 waves): s1/s2 shfl-reduction + bf16 fragment-packed Whp +
// per-head unmasked max of s2 via atomicMax (softmax shift bound).
// ---------------------------------------------------------------------------
__global__ __launch_bounds__(256, 2) void gemm1_kernel(
    const float* __restrict__ A,
    const unsigned short* __restrict__ BpHi, const unsigned short* __restrict__ BpLo,
    const float* __restrict__ avec,
    unsigned short* __restrict__ Whp, float* __restrict__ s1, float* __restrict__ s2,
    unsigned* __restrict__ Mmax) {
    __shared__ float accred[2][64][20];  // [rowhalf][col][16 rows + pad]
    const int bx   = blockIdx.x;   // 512
    const int h    = bx >> 6;
    const int mt   = bx & 63;
    const int tid  = threadIdx.x;
    const int wave = tid >> 6;
    const int lane = tid & 63;
    const int quad = lane >> 4;
    const int m16  = lane & 15;
    const int rw   = wave & 1;   // row half (16 rows each)
    const int kw   = wave >> 1;  // K half (256 each)
    const int rowbase = mt * 32 + rw * 16;

    const float* Arow = A + (long)(rowbase + m16) * 512 + kw * 256 + quad * 8;
    const long boff = ((long)(h * 16 + kw * 8) * 64 + m16) * 32 + quad * 8;
    const unsigned short* BH = BpHi + boff;
    const unsigned short* BL = BpLo + boff;

    f32x4 acc[4];
#pragma unroll
    for (int t = 0; t < 4; ++t)
#pragma unroll
        for (int r = 0; r < 4; ++r) acc[t][r] = 0.f;

    for (int kb = 0; kb < 8; ++kb) {
        const float* ap = Arow + kb * 32;
        bf16x8 ahi, alo;
#pragma unroll
        for (int j = 0; j < 8; ++j) {
            float v = ap[j];
            unsigned short hv = f2bf(v);
            ahi[j] = (short)hv;
            alo[j] = (short)f2bf(v - bf2f(hv));
        }
        const unsigned short* bh0 = BH + (long)kb * 2048;
        const unsigned short* bl0 = BL + (long)kb * 2048;
#pragma unroll
        for (int t = 0; t < 4; ++t) {
            bf16x8 bh = *reinterpret_cast<const bf16x8*>(bh0 + t * 512);
            bf16x8 bl = *reinterpret_cast<const bf16x8*>(bl0 + t * 512);
            acc[t] = __builtin_amdgcn_mfma_f32_16x16x32_bf16(alo, bh, acc[t], 0, 0, 0);
            acc[t] = __builtin_amdgcn_mfma_f32_16x16x32_bf16(ahi, bl, acc[t], 0, 0, 0);
            acc[t] = __builtin_amdgcn_mfma_f32_16x16x32_bf16(ahi, bh, acc[t], 0, 0, 0);
        }
    }

    if (kw == 1) {
#pragma unroll
        for (int t = 0; t < 4; ++t)
            *reinterpret_cast<f32x4*>(&accred[rw][t * 16 + m16][quad * 4]) = acc[t];
    }
    __syncthreads();
    if (kw == 1) return;

#pragma unroll
    for (int t = 0; t < 4; ++t) {
        f32x4 o = *reinterpret_cast<const f32x4*>(&accred[rw][t * 16 + m16][quad * 4]);
#pragma unroll
        for (int r = 0; r < 4; ++r) acc[t][r] += o[r];
    }

    // ---- s1/s2 epilogue ----
    float aS[4], aD[4];
#pragma unroll
    for (int t = 0; t < 4; ++t) {
        aS[t] = avec[(h << 7) + t * 16 + m16];
        aD[t] = avec[(h << 7) + 64 + t * 16 + m16];
    }
    float s2max = -INFINITY;
#pragma unroll
    for (int r = 0; r < 4; ++r) {
        float t1 = 0.f, t2 = 0.f;
#pragma unroll
        for (int t = 0; t < 4; ++t) {
            float v = acc[t][r];
            t1 = fmaf(v, aS[t], t1);
            t2 = fmaf(v, aD[t], t2);
        }
#pragma unroll
        for (int off = 1; off < 16; off <<= 1) {
            t1 += __shfl_xor(t1, off);
            t2 += __shfl_xor(t2, off);
        }
        s2max = fmaxf(s2max, t2);
        if (m16 == 0) {
            int row = rowbase + quad * 4 + r;
            s1[(h << 11) + row] = t1;
            s2[(h << 11) + row] = t2;
        }
    }
    // per-head unmasked max of s2 (upper bound for softmax shift)
    s2max = fmaxf(s2max, __shfl_xor(s2max, 16));
    s2max = fmaxf(s2max, __shfl_xor(s2max, 32));
    if (lane == 0) atomicMax(Mmax + h, fkey(s2max));

    // ---- store Wh bf16 fragment-packed (Hi only; PV tolerates bf16) ----
#pragma unroll
    for (int t = 0; t < 4; ++t) {
        const int col = t * 16 + m16;
#pragma unroll
        for (int r = 0; r < 4; ++r) {
            const int row = rowbase + quad * 4 + r;
            long idx = (((long)(h * 64 + (row >> 5)) * 64 + col) << 5) + (row & 31);
            Whp[idx] = f2bf(acc[t][r]);
        }
    }
}

// ---------------------------------------------------------------------------
// Fused attention, 2 passes (P1 max-scan eliminated via per-head s2 bound):
//  P2: l = sum of masked exp(e - m), m = lrelu(s1_i + max_h s2) (upper bound;
//      softmax is shift-invariant). All-masked rows detected by l == 0.
//  P3: att write (LDS-staged packed NT stores) + PV MFMA (bf16 P).
// Block = 256 thr (4 waves), 16 rows; each wave owns a j-quarter.
// ---------------------------------------------------------------------------
__global__ __launch_bounds__(256, 4) void fused_att_kernel(
    const float* __restrict__ s1g, const float* __restrict__ s2g,
    const unsigned int* __restrict__ gbits,
    const unsigned short* __restrict__ Whp,
    const unsigned* __restrict__ Mmax,
    float* __restrict__ att, float* __restrict__ hout) {
    __shared__ unsigned int lbits[16 * 65];   // 16 rows x 64 words, +1 pad
    __shared__ float ls2[2048];
    __shared__ float lsum[4][16];
    __shared__ float accred[3][64][20];       // waves 1..3 partial PV
    __shared__ f32x4 pstage[4][16][9];        // per-wave P staging

    const int bx   = blockIdx.x;   // 1024
    const int h    = bx >> 7;
    const int row0 = (bx & 127) << 4;
    const int tid  = threadIdx.x;
    const int wq   = tid >> 6;     // wave = j-quarter
    const int lane = tid & 63;
    const int quad = lane >> 4;
    const int m16  = lane & 15;

    // stage adj bits (16 rows x 64 words) + s2 (2048 f32)
#pragma unroll
    for (int i = 0; i < 4; ++i) {
        int idx = i * 256 + tid;
        lbits[(idx >> 6) * 65 + (idx & 63)] = gbits[((row0 + (idx >> 6)) << 6) + (idx & 63)];
    }
    const float4* s2v4 = reinterpret_cast<const float4*>(s2g + (h << 11));
#pragma unroll
    for (int i = 0; i < 2; ++i) {
        int idx = i * 256 + tid;
        reinterpret_cast<float4*>(ls2)[idx] = s2v4[idx];
    }
    __syncthreads();

    const float s1i = s1g[(h << 11) + row0 + m16];
    const float M = funkey(Mmax[h]);
    const float ebar = s1i + M;
    const float m = fmaxf(ebar, 0.2f * ebar);  // lrelu(bound) >= all masked lrelu(e)

    // ---- P2: l = sum of exp(e-m) over allowed j ----
    float lp = 0.f;
    for (int i = 0; i < 16; ++i) {
        const int jt = wq * 16 + i;
        unsigned int word = lbits[m16 * 65 + jt];
        float4 sa = *reinterpret_cast<const float4*>(ls2 + jt * 32 + quad * 8);
        float4 sb = *reinterpret_cast<const float4*>(ls2 + jt * 32 + quad * 8 + 4);
        float sv[8] = {sa.x, sa.y, sa.z, sa.w, sb.x, sb.y, sb.z, sb.w};
#pragma unroll
        for (int u = 0; u < 8; ++u) {
            float e = s1i + sv[u];
            e = fmaxf(e, 0.2f * e);
            lp += ((word >> (quad * 8 + u)) & 1u) ? __expf(e - m) : 0.f;
        }
    }
    lp += __shfl_xor(lp, 16);
    lp += __shfl_xor(lp, 32);
    if (lane < 16) lsum[wq][m16] = lp;
    __syncthreads();
    const float l = lsum[0][m16] + lsum[1][m16] + lsum[2][m16] + lsum[3][m16];
    const bool am = (l == 0.f);                // all-masked row
    const float invl = am ? 0.f : 1.f / l;
    const float fallb = 1.f / 2048.f;

    // ---- P3: att write (LDS-staged, coalesced) + PV MFMA over j-quarter ----
    f32x4 acc[4];
#pragma unroll
    for (int t = 0; t < 4; ++t)
#pragma unroll
        for (int r = 0; r < 4; ++r) acc[t][r] = 0.f;

    const unsigned short* BW = Whp + ((long)(h << 12) + m16) * 32 + quad * 8;
    float* attbase = att + (long)h * 4194304 + (long)row0 * 2048;
    const int fr = lane >> 3;        // flush row within half (0..7)
    const int fc = lane & 7;         // flush col-block (16B units)

    for (int i = 0; i < 16; ++i) {
        const int jt = wq * 16 + i;
        unsigned int word = lbits[m16 * 65 + jt];
        float4 sa = *reinterpret_cast<const float4*>(ls2 + jt * 32 + quad * 8);
        float4 sb = *reinterpret_cast<const float4*>(ls2 + jt * 32 + quad * 8 + 4);
        float sv[8] = {sa.x, sa.y, sa.z, sa.w, sb.x, sb.y, sb.z, sb.w};
        float p[8];
        bf16x8 af;
#pragma unroll
        for (int u = 0; u < 8; ++u) {
            float e = s1i + sv[u];
            e = fmaxf(e, 0.2f * e);
            float pv = ((word >> (quad * 8 + u)) & 1u) ? __expf(e - m) * invl : 0.f;
            p[u] = am ? fallb : pv;
            af[u] = (short)f2bf(p[u]);
        }
        // stage P-tile (fragment layout -> row-major) in this wave's LDS region
        f32x4 plo, phi;
        plo[0] = p[0]; plo[1] = p[1]; plo[2] = p[2]; plo[3] = p[3];
        phi[0] = p[4]; phi[1] = p[5]; phi[2] = p[6]; phi[3] = p[7];
        pstage[wq][m16][quad * 2]     = plo;
        pstage[wq][m16][quad * 2 + 1] = phi;

        const unsigned short* b0 = BW + (long)jt * 2048;
#pragma unroll
        for (int t = 0; t < 4; ++t) {
            bf16x8 bf = *reinterpret_cast<const bf16x8*>(b0 + t * 512);
            acc[t] = __builtin_amdgcn_mfma_f32_16x16x32_bf16(af, bf, acc[t], 0, 0, 0);
        }

        // packed flush: 2 wave-stores, each 8 rows x 128B full lines (NT)
#pragma unroll
        for (int half = 0; half < 2; ++half) {
            const int r = half * 8 + fr;
            f32x4 v = pstage[wq][r][fc];
            __builtin_nontemporal_store(
                v, reinterpret_cast<f32x4*>(attbase + (long)r * 2048 + jt * 32 + fc * 4));
        }
    }

    // ---- reduce partial PV across waves, epilogue by wave 0 ----
    if (wq > 0) {
#pragma unroll
        for (int t = 0; t < 4; ++t)
            *reinterpret_cast<f32x4*>(&accred[wq - 1][t * 16 + m16][quad * 4]) = acc[t];
    }
    __syncthreads();
    if (wq == 0) {
#pragma unroll
        for (int t = 0; t < 4; ++t) {
            const int col = t * 16 + m16;
#pragma unroll
            for (int w = 0; w < 3; ++w) {
                f32x4 o = *reinterpret_cast<const f32x4*>(&accred[w][col][quad * 4]);
#pragma unroll
                for (int r = 0; r < 4; ++r) acc[t][r] += o[r];
            }
#pragma unroll
            for (int r = 0; r < 4; ++r) {
                const int row = row0 + quad * 4 + r;
                hout[(row << 9) + (h << 6) + col] = elu1(elu1(acc[t][r]));
            }
        }
    }
}

// ---------------------------------------------------------------------------
extern "C" void kernel_launch(void* const* d_in, const int* in_sizes, int n_in,
                              void* d_out, int out_size, void* d_ws, size_t ws_size,
                              hipStream_t stream) {
    const float* x  = (const float*)d_in[0];   // [2048][512]
    const int* adj  = (const int*)d_in[1];     // [2048][2048]
    const float* W1 = (const float*)d_in[2];   // [8][512][64]
    const float* a1 = (const float*)d_in[3];   // [8][128]
    const float* W2 = (const float*)d_in[4];
    const float* a2 = (const float*)d_in[5];

    float* out  = (float*)d_out;       // h2 [2048][512]
    float* att1 = out + 1048576;       // [8][2048][2048]
    float* att2 = att1 + 33554432;

    char* w = (char*)d_ws;
    unsigned short* WpHi  = (unsigned short*)(w);             // 512 KB
    unsigned short* WpLo  = (unsigned short*)(w + 524288);    // 512 KB
    unsigned short* Whp   = (unsigned short*)(w + 1048576);   // 2 MB
    float* s1             = (float*)(w + 3145728);            // 64 KB
    float* s2             = (float*)(w + 3211264);            // 64 KB
    unsigned long long* gbits = (unsigned long long*)(w + 3276800);  // 512 KB
    float* x2             = (float*)(w + 3801088);            // 4 MB
    unsigned* Mmax        = (unsigned*)(w + 7995392);         // 32 B

    const unsigned int* gbits32 = (const unsigned int*)gbits;

    adjbits_kernel<<<16384, 256, 0, stream>>>(adj, gbits);

    // ---- layer 1 ----
    reorder_w_kernel<<<1024, 256, 0, stream>>>(W1, WpHi, WpLo, Mmax);
    gemm1_kernel<<<512, 256, 0, stream>>>(x, WpHi, WpLo, a1, Whp, s1, s2, Mmax);
    fused_att_kernel<<<1024, 256, 0, stream>>>(s1, s2, gbits32, Whp, Mmax, att1, x2);

    // ---- layer 2 ----
    reorder_w_kernel<<<1024, 256, 0, stream>>>(W2, WpHi, WpLo, Mmax);
    gemm1_kernel<<<512, 256, 0, stream>>>(x2, WpHi, WpLo, a2, Whp, s1, s2, Mmax);
    fused_att_kernel<<<1024, 256, 0, stream>>>(s1, s2, gbits32, Whp, Mmax, att2, out);
}

// Round 4
// 358.529 us; speedup vs baseline: 1.1315x; 1.0502x over previous
//
#include <hip/hip_runtime.h>
#include <hip/hip_bf16.h>

// GAT (2-layer, 8-head) on gfx950. Inputs f32 (adj int32), outputs f32.
// d_out = [h2: 2048*512 | att1: 8*2048*2048 | att2: 8*2048*2048] float32.

typedef __attribute__((ext_vector_type(8))) short bf16x8;
typedef __attribute__((ext_vector_type(4))) float f32x4;

__device__ __forceinline__ float bf2f(unsigned short u) {
    return __uint_as_float(((unsigned int)u) << 16);
}
__device__ __forceinline__ unsigned short f2bf(float f) {
    __hip_bfloat16 h = __float2bfloat16(f);
    return __builtin_bit_cast(unsigned short, h);
}
__device__ __forceinline__ float elu1(float x) { return x > 0.f ? x : expm1f(x); }

// ---------------------------------------------------------------------------
// adj [2048][2048] int32 -> bitmask [2048][64] u32 (u64 stores via ballot).
// ---------------------------------------------------------------------------
__global__ __launch_bounds__(256) void adjbits_kernel(
    const int* __restrict__ adj, unsigned long long* __restrict__ gbits) {
    int g = blockIdx.x * 256 + threadIdx.x;  // 4194304 threads
    unsigned long long m = __ballot(adj[g] > 0);
    if ((threadIdx.x & 63) == 0) gbits[g >> 6] = m;
}

// ---------------------------------------------------------------------------
// Reorder W [8][512][64] (f32) into split-bf16 MFMA B-fragment packing:
// Wp{Hi,Lo}[h][kb][col][k&31], k = kb*32 + (quad*8+j).
// ---------------------------------------------------------------------------
__global__ __launch_bounds__(256) void reorder_w_kernel(
    const float* __restrict__ W, unsigned short* __restrict__ WpHi,
    unsigned short* __restrict__ WpLo) {
    int i = blockIdx.x * 256 + threadIdx.x;  // 262144 threads
    int o = i & 63;
    int k = (i >> 6) & 511;
    int h = i >> 15;
    float v = W[i];
    unsigned short hi = f2bf(v);
    unsigned short lo = f2bf(v - bf2f(hi));
    long idx = (((h * 16) + (k >> 5)) * 64 + o) * 32 + (k & 31);
    WpHi[idx] = hi;
    WpLo[idx] = lo;
}

// ---------------------------------------------------------------------------
// GEMM1: Wh[h] = A[2048][512](f32) @ W[h][512][64], split-bf16 (3 MFMAs).
// 2-way K-split: block = 4 waves over (2 row-halves x 2 K-halves), 32 rows.
// Grid = 8 heads * 64 row-tiles = 512 blocks. LDS-reduce K partials.
// Epilogue (kw==0 waves): s1/s2 shfl-reduction + bf16 fragment-packed Whp.
// ---------------------------------------------------------------------------
__global__ __launch_bounds__(256, 2) void gemm1_kernel(
    const float* __restrict__ A,
    const unsigned short* __restrict__ BpHi, const unsigned short* __restrict__ BpLo,
    const float* __restrict__ avec,
    unsigned short* __restrict__ Whp, float* __restrict__ s1, float* __restrict__ s2) {
    __shared__ float accred[2][64][20];  // [rowhalf][col][16 rows + pad]
    const int bx   = blockIdx.x;   // 512
    const int h    = bx >> 6;
    const int mt   = bx & 63;
    const int tid  = threadIdx.x;
    const int wave = tid >> 6;
    const int lane = tid & 63;
    const int quad = lane >> 4;
    const int m16  = lane & 15;
    const int rw   = wave & 1;   // row half (16 rows each)
    const int kw   = wave >> 1;  // K half (256 each)
    const int rowbase = mt * 32 + rw * 16;

    const float* Arow = A + (long)(rowbase + m16) * 512 + kw * 256 + quad * 8;
    const long boff = ((long)(h * 16 + kw * 8) * 64 + m16) * 32 + quad * 8;
    const unsigned short* BH = BpHi + boff;
    const unsigned short* BL = BpLo + boff;

    f32x4 acc[4];
#pragma unroll
    for (int t = 0; t < 4; ++t)
#pragma unroll
        for (int r = 0; r < 4; ++r) acc[t][r] = 0.f;

    for (int kb = 0; kb < 8; ++kb) {
        const float* ap = Arow + kb * 32;
        bf16x8 ahi, alo;
#pragma unroll
        for (int j = 0; j < 8; ++j) {
            float v = ap[j];
            unsigned short hv = f2bf(v);
            ahi[j] = (short)hv;
            alo[j] = (short)f2bf(v - bf2f(hv));
        }
        const unsigned short* bh0 = BH + (long)kb * 2048;
        const unsigned short* bl0 = BL + (long)kb * 2048;
#pragma unroll
        for (int t = 0; t < 4; ++t) {
            bf16x8 bh = *reinterpret_cast<const bf16x8*>(bh0 + t * 512);
            bf16x8 bl = *reinterpret_cast<const bf16x8*>(bl0 + t * 512);
            acc[t] = __builtin_amdgcn_mfma_f32_16x16x32_bf16(alo, bh, acc[t], 0, 0, 0);
            acc[t] = __builtin_amdgcn_mfma_f32_16x16x32_bf16(ahi, bl, acc[t], 0, 0, 0);
            acc[t] = __builtin_amdgcn_mfma_f32_16x16x32_bf16(ahi, bh, acc[t], 0, 0, 0);
        }
    }

    if (kw == 1) {
#pragma unroll
        for (int t = 0; t < 4; ++t)
            *reinterpret_cast<f32x4*>(&accred[rw][t * 16 + m16][quad * 4]) = acc[t];
    }
    __syncthreads();
    if (kw == 1) return;

#pragma unroll
    for (int t = 0; t < 4; ++t) {
        f32x4 o = *reinterpret_cast<const f32x4*>(&accred[rw][t * 16 + m16][quad * 4]);
#pragma unroll
        for (int r = 0; r < 4; ++r) acc[t][r] += o[r];
    }

    // ---- s1/s2 epilogue ----
    float aS[4], aD[4];
#pragma unroll
    for (int t = 0; t < 4; ++t) {
        aS[t] = avec[(h << 7) + t * 16 + m16];
        aD[t] = avec[(h << 7) + 64 + t * 16 + m16];
    }
#pragma unroll
    for (int r = 0; r < 4; ++r) {
        float t1 = 0.f, t2 = 0.f;
#pragma unroll
        for (int t = 0; t < 4; ++t) {
            float v = acc[t][r];
            t1 = fmaf(v, aS[t], t1);
            t2 = fmaf(v, aD[t], t2);
        }
#pragma unroll
        for (int off = 1; off < 16; off <<= 1) {
            t1 += __shfl_xor(t1, off);
            t2 += __shfl_xor(t2, off);
        }
        if (m16 == 0) {
            int row = rowbase + quad * 4 + r;
            s1[(h << 11) + row] = t1;
            s2[(h << 11) + row] = t2;
        }
    }

    // ---- store Wh bf16 fragment-packed (Hi only; PV tolerates bf16) ----
#pragma unroll
    for (int t = 0; t < 4; ++t) {
        const int col = t * 16 + m16;
#pragma unroll
        for (int r = 0; r < 4; ++r) {
            const int row = rowbase + quad * 4 + r;
            long idx = (((long)(h * 64 + (row >> 5)) * 64 + col) << 5) + (row & 31);
            Whp[idx] = f2bf(acc[t][r]);
        }
    }
}

// ---------------------------------------------------------------------------
// Fused attention, 2 passes:
//  P12: ONLINE masked softmax scan (exact per-row max + sum in one pass;
//       per-8-block tile max, rescale only when max increases).
//  P3 : att write (LDS-staged packed NT stores) + PV MFMA (bf16 P).
// Block = 256 thr (4 waves), 16 rows; each wave owns a j-quarter.
// ---------------------------------------------------------------------------
__global__ __launch_bounds__(256, 4) void fused_att_kernel(
    const float* __restrict__ s1g, const float* __restrict__ s2g,
    const unsigned int* __restrict__ gbits,
    const unsigned short* __restrict__ Whp,
    float* __restrict__ att, float* __restrict__ hout) {
    __shared__ unsigned int lbits[16 * 65];   // 16 rows x 64 words, +1 pad
    __shared__ float ls2[2048];
    __shared__ float lmax[4][16];
    __shared__ float lsum[4][16];
    __shared__ float accred[3][64][20];       // waves 1..3 partial PV
    __shared__ f32x4 pstage[4][16][9];        // per-wave P staging

    const int bx   = blockIdx.x;   // 1024
    const int h    = bx >> 7;
    const int row0 = (bx & 127) << 4;
    const int tid  = threadIdx.x;
    const int wq   = tid >> 6;     // wave = j-quarter
    const int lane = tid & 63;
    const int quad = lane >> 4;
    const int m16  = lane & 15;

    // stage adj bits (16 rows x 64 words) + s2 (2048 f32)
#pragma unroll
    for (int i = 0; i < 4; ++i) {
        int idx = i * 256 + tid;
        lbits[(idx >> 6) * 65 + (idx & 63)] = gbits[((row0 + (idx >> 6)) << 6) + (idx & 63)];
    }
    const float4* s2v4 = reinterpret_cast<const float4*>(s2g + (h << 11));
#pragma unroll
    for (int i = 0; i < 2; ++i) {
        int idx = i * 256 + tid;
        reinterpret_cast<float4*>(ls2)[idx] = s2v4[idx];
    }
    __syncthreads();

    const float s1i = s1g[(h << 11) + row0 + m16];

    // ---- P12: fused online masked max+sum over this wave's 16 words ----
    float mx = -INFINITY;
    float lp = 0.f;
    for (int i = 0; i < 16; ++i) {
        const int jt = wq * 16 + i;
        unsigned int word = lbits[m16 * 65 + jt] >> (quad * 8);
        float4 sa = *reinterpret_cast<const float4*>(ls2 + jt * 32 + quad * 8);
        float4 sb = *reinterpret_cast<const float4*>(ls2 + jt * 32 + quad * 8 + 4);
        float sv[8] = {sa.x, sa.y, sa.z, sa.w, sb.x, sb.y, sb.z, sb.w};
        float ev[8];
        float bm = -INFINITY;
#pragma unroll
        for (int u = 0; u < 8; ++u) {
            float e = s1i + sv[u];
            e = fmaxf(e, 0.2f * e);
            ev[u] = e;
            bm = fmaxf(bm, ((word >> u) & 1u) ? e : -INFINITY);
        }
        float nm = fmaxf(mx, bm);
        float sc = (mx == nm) ? 1.f : __expf(mx - nm);  // -inf==-inf -> 1 (no NaN)
        lp *= sc;
        mx = nm;
#pragma unroll
        for (int u = 0; u < 8; ++u)
            lp += ((word >> u) & 1u) ? __expf(ev[u] - mx) : 0.f;
    }
    // merge across the 4 quads of each row (lanes l, l^16, l^32, l^48)
#pragma unroll
    for (int off = 16; off < 64; off <<= 1) {
        float omx = __shfl_xor(mx, off);
        float olp = __shfl_xor(lp, off);
        float nm = fmaxf(mx, omx);
        float sa = (mx == nm) ? 1.f : __expf(mx - nm);
        float sb = (omx == nm) ? 1.f : __expf(omx - nm);
        lp = fmaf(lp, sa, olp * sb);
        mx = nm;
    }
    if (lane < 16) {
        lmax[wq][m16] = mx;
        lsum[wq][m16] = lp;
    }
    __syncthreads();
    // block-level merge over the 4 wave-quarters
    float m = fmaxf(fmaxf(lmax[0][m16], lmax[1][m16]),
                    fmaxf(lmax[2][m16], lmax[3][m16]));
    float l = 0.f;
#pragma unroll
    for (int w = 0; w < 4; ++w) {
        float wm = lmax[w][m16];
        float ws = (wm == m) ? 1.f : __expf(wm - m);
        l = fmaf(lsum[w][m16], ws, l);
    }
    const bool am = (m == -INFINITY);          // all-masked row
    const float invl = am ? 0.f : 1.f / l;
    const float fallb = 1.f / 2048.f;

    // ---- P3: att write (LDS-staged, coalesced) + PV MFMA over j-quarter ----
    f32x4 acc[4];
#pragma unroll
    for (int t = 0; t < 4; ++t)
#pragma unroll
        for (int r = 0; r < 4; ++r) acc[t][r] = 0.f;

    const unsigned short* BW = Whp + ((long)(h << 12) + m16) * 32 + quad * 8;
    float* attbase = att + (long)h * 4194304 + (long)row0 * 2048;
    const int fr = lane >> 3;        // flush row within half (0..7)
    const int fc = lane & 7;         // flush col-block (16B units)

    for (int i = 0; i < 16; ++i) {
        const int jt = wq * 16 + i;
        unsigned int word = lbits[m16 * 65 + jt];
        float4 sa = *reinterpret_cast<const float4*>(ls2 + jt * 32 + quad * 8);
        float4 sb = *reinterpret_cast<const float4*>(ls2 + jt * 32 + quad * 8 + 4);
        float sv[8] = {sa.x, sa.y, sa.z, sa.w, sb.x, sb.y, sb.z, sb.w};
        float p[8];
        bf16x8 af;
#pragma unroll
        for (int u = 0; u < 8; ++u) {
            float e = s1i + sv[u];
            e = fmaxf(e, 0.2f * e);
            float pv = ((word >> (quad * 8 + u)) & 1u) ? __expf(e - m) * invl : 0.f;
            p[u] = am ? fallb : pv;
            af[u] = (short)f2bf(p[u]);
        }
        // stage P-tile (fragment layout -> row-major) in this wave's LDS region
        f32x4 plo, phi;
        plo[0] = p[0]; plo[1] = p[1]; plo[2] = p[2]; plo[3] = p[3];
        phi[0] = p[4]; phi[1] = p[5]; phi[2] = p[6]; phi[3] = p[7];
        pstage[wq][m16][quad * 2]     = plo;
        pstage[wq][m16][quad * 2 + 1] = phi;

        const unsigned short* b0 = BW + (long)jt * 2048;
#pragma unroll
        for (int t = 0; t < 4; ++t) {
            bf16x8 bf = *reinterpret_cast<const bf16x8*>(b0 + t * 512);
            acc[t] = __builtin_amdgcn_mfma_f32_16x16x32_bf16(af, bf, acc[t], 0, 0, 0);
        }

        // packed flush: 2 wave-stores, each 8 rows x 128B full lines (NT)
#pragma unroll
        for (int half = 0; half < 2; ++half) {
            const int r = half * 8 + fr;
            f32x4 v = pstage[wq][r][fc];
            __builtin_nontemporal_store(
                v, reinterpret_cast<f32x4*>(attbase + (long)r * 2048 + jt * 32 + fc * 4));
        }
    }

    // ---- reduce partial PV across waves, epilogue by wave 0 ----
    if (wq > 0) {
#pragma unroll
        for (int t = 0; t < 4; ++t)
            *reinterpret_cast<f32x4*>(&accred[wq - 1][t * 16 + m16][quad * 4]) = acc[t];
    }
    __syncthreads();
    if (wq == 0) {
#pragma unroll
        for (int t = 0; t < 4; ++t) {
            const int col = t * 16 + m16;
#pragma unroll
            for (int w = 0; w < 3; ++w) {
                f32x4 o = *reinterpret_cast<const f32x4*>(&accred[w][col][quad * 4]);
#pragma unroll
                for (int r = 0; r < 4; ++r) acc[t][r] += o[r];
            }
#pragma unroll
            for (int r = 0; r < 4; ++r) {
                const int row = row0 + quad * 4 + r;
                hout[(row << 9) + (h << 6) + col] = elu1(elu1(acc[t][r]));
            }
        }
    }
}

// ---------------------------------------------------------------------------
extern "C" void kernel_launch(void* const* d_in, const int* in_sizes, int n_in,
                              void* d_out, int out_size, void* d_ws, size_t ws_size,
                              hipStream_t stream) {
    const float* x  = (const float*)d_in[0];   // [2048][512]
    const int* adj  = (const int*)d_in[1];     // [2048][2048]
    const float* W1 = (const float*)d_in[2];   // [8][512][64]
    const float* a1 = (const float*)d_in[3];   // [8][128]
    const float* W2 = (const float*)d_in[4];
    const float* a2 = (const float*)d_in[5];

    float* out  = (float*)d_out;       // h2 [2048][512]
    float* att1 = out + 1048576;       // [8][2048][2048]
    float* att2 = att1 + 33554432;

    char* w = (char*)d_ws;
    unsigned short* WpHi  = (unsigned short*)(w);             // 512 KB
    unsigned short* WpLo  = (unsigned short*)(w + 524288);    // 512 KB
    unsigned short* Whp   = (unsigned short*)(w + 1048576);   // 2 MB
    float* s1             = (float*)(w + 3145728);            // 64 KB
    float* s2             = (float*)(w + 3211264);            // 64 KB
    unsigned long long* gbits = (unsigned long long*)(w + 3276800);  // 512 KB
    float* x2             = (float*)(w + 3801088);            // 4 MB -> ends ~7.8 MB

    const unsigned int* gbits32 = (const unsigned int*)gbits;

    adjbits_kernel<<<16384, 256, 0, stream>>>(adj, gbits);

    // ---- layer 1 ----
    reorder_w_kernel<<<1024, 256, 0, stream>>>(W1, WpHi, WpLo);
    gemm1_kernel<<<512, 256, 0, stream>>>(x, WpHi, WpLo, a1, Whp, s1, s2);
    fused_att_kernel<<<1024, 256, 0, stream>>>(s1, s2, gbits32, Whp, att1, x2);

    // ---- layer 2 ----
    reorder_w_kernel<<<1024, 256, 0, stream>>>(W2, WpHi, WpLo);
    gemm1_kernel<<<512, 256, 0, stream>>>(x2, WpHi, WpLo, a2, Whp, s1, s2);
    fused_att_kernel<<<1024, 256, 0, stream>>>(s1, s2, gbits32, Whp, att2, out);
}